// Round 22
// baseline (306.917 us; speedup 1.0000x reference)
//
#include <hip/hip_runtime.h>
#include <math.h>

#define F 128
#define OUTDIM 64
#define NEG 0.2f

typedef __attribute__((ext_vector_type(8))) short bf16x8;
typedef __attribute__((ext_vector_type(4))) float f32x4;

// ---------------- bf16 helpers ----------------
__device__ __forceinline__ float blo(unsigned u) { return __uint_as_float(u << 16); }
__device__ __forceinline__ float bhi(unsigned u) { return __uint_as_float(u & 0xFFFF0000u); }
__device__ __forceinline__ unsigned bpack(float a, float b) {  // rtne both
    unsigned ua = __float_as_uint(a), ub = __float_as_uint(b);
    ua += 0x7FFFu + ((ua >> 16) & 1u);
    ub += 0x7FFFu + ((ub >> 16) & 1u);
    return (ua >> 16) | (ub & 0xFFFF0000u);
}

// ---------------- utility ----------------
__global__ void zero_ints(int* __restrict__ p, int n) {
    int i = blockIdx.x * blockDim.x + threadIdx.x;
    if (i < n) p[i] = 0;
}

// ---------------- CSR build ----------------
// hist records each edge's arrival rank (atomicAdd return) so scatter needs NO atomics.
__global__ void hist_kernel(const int* __restrict__ src, const int* __restrict__ dst,
                            int* __restrict__ degF, int* __restrict__ degR,
                            int* __restrict__ rankF, int* __restrict__ rankR, int E) {
    int e = blockIdx.x * blockDim.x + threadIdx.x;
    if (e < E) {
        rankF[e] = atomicAdd(&degF[dst[e]], 1);
        rankR[e] = atomicAdd(&degR[src[e]], 1);
    }
}

__global__ void scan_pass1(const int* __restrict__ degF, const int* __restrict__ degR,
                           int* __restrict__ rsF, int* __restrict__ rsR,
                           int* __restrict__ bsums, int N) {
    const int arr = blockIdx.y;
    const int* deg = arr ? degR : degF;
    int* rs = arr ? rsR : rsF;
    int tid = threadIdx.x;
    int base = blockIdx.x * 1024 + tid * 4;
    int v[4];
#pragma unroll
    for (int i = 0; i < 4; i++) v[i] = (base + i < N) ? deg[base + i] : 0;
    int s1 = v[0] + v[1] + v[2] + v[3];
    __shared__ int sd[256];
    sd[tid] = s1;
    __syncthreads();
    for (int off = 1; off < 256; off <<= 1) {
        int t = (tid >= off) ? sd[tid - off] : 0;
        __syncthreads();
        sd[tid] += t;
        __syncthreads();
    }
    int run = sd[tid] - s1;
#pragma unroll
    for (int i = 0; i < 4; i++) {
        run += v[i];
        if (base + i < N) rs[base + i + 1] = run;
    }
    if (tid == 255) bsums[arr * 128 + blockIdx.x] = sd[255];
    if (tid == 0 && blockIdx.x == 0) rs[0] = 0;
}

__global__ void scan_pass2(int* __restrict__ bsums, int nb) {
    int arr = blockIdx.y;
    int tid = threadIdx.x;  // 128
    __shared__ int sd[128];
    int v = (tid < nb) ? bsums[arr * 128 + tid] : 0;
    sd[tid] = v;
    __syncthreads();
    for (int off = 1; off < 128; off <<= 1) {
        int t = (tid >= off) ? sd[tid - off] : 0;
        __syncthreads();
        sd[tid] += t;
        __syncthreads();
    }
    bsums[arr * 128 + tid] = sd[tid];
}

__global__ void scan_pass3(int* __restrict__ rsF, int* __restrict__ rsR,
                           const int* __restrict__ bsums, int N) {
    int arr = blockIdx.y;
    if (blockIdx.x == 0) return;
    int* rs = arr ? rsR : rsF;
    int off = bsums[arr * 128 + blockIdx.x - 1];
    int base = blockIdx.x * 1024 + threadIdx.x * 4;
#pragma unroll
    for (int i = 0; i < 4; i++)
        if (base + i < N) rs[base + i + 1] += off;
}

// atomic-free: position = rs[node] + precomputed rank
__global__ void scatter_kernel(const int* __restrict__ src, const int* __restrict__ dst,
                               const int* __restrict__ rsF, const int* __restrict__ rsR,
                               const int* __restrict__ rankF, const int* __restrict__ rankR,
                               int* __restrict__ colF, int* __restrict__ colR, int E) {
    int e = blockIdx.x * blockDim.x + threadIdx.x;
    if (e < E) {
        int s = src[e], d = dst[e];
        colF[rsF[d] + rankF[e]] = s;
        colR[rsR[s] + rankR[e]] = d;
    }
}

// ---------------- per-node attention scalars + bf16 feature copy ----------------
__global__ void sd4_kernel(const float* __restrict__ x,
                           const float* __restrict__ af_s, const float* __restrict__ af_d,
                           const float* __restrict__ ar_s, const float* __restrict__ ar_d,
                           float* __restrict__ sf, float* __restrict__ df,
                           float* __restrict__ sr, float* __restrict__ dr,
                           unsigned* __restrict__ xbf, int N) {
    int node = blockIdx.x * 4 + (threadIdx.x >> 6);
    int lane = threadIdx.x & 63;
    if (node >= N) return;
    const float2 xv = *(const float2*)&x[(size_t)node * F + 2 * lane];
    xbf[(size_t)node * 64 + lane] = bpack(xv.x, xv.y);
    float2 a;
    a = *(const float2*)&af_s[2 * lane]; float vsf = xv.x * a.x + xv.y * a.y;
    a = *(const float2*)&af_d[2 * lane]; float vdf = xv.x * a.x + xv.y * a.y;
    a = *(const float2*)&ar_s[2 * lane]; float vsr = xv.x * a.x + xv.y * a.y;
    a = *(const float2*)&ar_d[2 * lane]; float vdr = xv.x * a.x + xv.y * a.y;
#pragma unroll
    for (int off = 32; off > 0; off >>= 1) {
        vsf += __shfl_xor(vsf, off);
        vdf += __shfl_xor(vdf, off);
        vsr += __shfl_xor(vsr, off);
        vdr += __shfl_xor(vdr, off);
    }
    if (lane == 0) { sf[node] = vsf; df[node] = vdf; sr[node] = vsr; dr[node] = vdr; }
}

// ---------------- fused dual-direction attention hop ----------------
// quarter-wave (16 lanes) per node; blockIdx.y selects direction.
// bf16 rows (256 B), 8-deep gather pipeline (raw uint4 staging).
struct AggDir {
    const unsigned* hin_bf;  // [N][64]  bf16x2
    const float* s;          // [N]
    const float* d;          // [N]
    const int* rs;           // [N+1]
    const int* col;          // [E]
    unsigned* hout_bf;       // [N][64]  bf16x2
    const float* a_s;        // nullable: fused next-hop dots
    const float* a_d;
    float* s_out;
    float* d_out;
};

__global__ __launch_bounds__(256) void agg_kernel(AggDir D0, AggDir D1, int N) {
    AggDir P = blockIdx.y ? D1 : D0;
    int node = blockIdx.x * 16 + (threadIdx.x >> 4);
    int lane = threadIdx.x & 15;           // within quarter-wave
    int qbase = threadIdx.x & 48;          // quarter offset inside the wave
    if (node >= N) return;
    float di = P.d[node];
    int beg = P.rs[node], end = P.rs[node + 1];
    int deg = end - beg;
    float m = -INFINITY, l = 0.f;
    float4 a0 = make_float4(0.f, 0.f, 0.f, 0.f);
    float4 a1 = make_float4(0.f, 0.f, 0.f, 0.f);

    for (int base = 0; base < deg; base += 16) {
        int cnt = min(16, deg - base);
        int sj_l = 0;
        float e_l = -INFINITY;
        if (lane < cnt) {
            sj_l = P.col[beg + base + lane];
            float e = P.s[sj_l] + di;
            e_l = (e >= 0.f) ? e : NEG * e;
        }
        float bm = e_l;
#pragma unroll
        for (int off = 8; off > 0; off >>= 1) bm = fmaxf(bm, __shfl_xor(bm, off));
        float nm = fmaxf(m, bm);
        float p_l = (lane < cnt) ? __expf(e_l - nm) : 0.f;
        float ps = p_l;
#pragma unroll
        for (int off = 8; off > 0; off >>= 1) ps += __shfl_xor(ps, off);
        float sc = (m == -INFINITY) ? 0.f : __expf(m - nm);
        l = l * sc + ps;
        a0.x *= sc; a0.y *= sc; a0.z *= sc; a0.w *= sc;
        a1.x *= sc; a1.y *= sc; a1.z *= sc; a1.w *= sc;
        // 8-deep gather: stage raw bf16x2 lines (uint4), convert at FMA time
        for (int j0 = 0; j0 < cnt; j0 += 8) {
            int sj[8]; float p[8]; uint4 hb[8];
#pragma unroll
            for (int u = 0; u < 8; u++) {
                sj[u] = __shfl(sj_l, qbase + j0 + u);
                p[u]  = __shfl(p_l,  qbase + j0 + u);
            }
#pragma unroll
            for (int u = 0; u < 8; u++) {
                if (j0 + u < cnt) {  // uniform per quarter-wave
                    hb[u] = *(const uint4*)&P.hin_bf[(size_t)sj[u] * 64 + 4 * lane];
                } else {
                    hb[u] = make_uint4(0u, 0u, 0u, 0u);
                }
            }
#pragma unroll
            for (int u = 0; u < 8; u++) {
                a0.x += p[u] * blo(hb[u].x); a0.y += p[u] * bhi(hb[u].x);
                a0.z += p[u] * blo(hb[u].y); a0.w += p[u] * bhi(hb[u].y);
                a1.x += p[u] * blo(hb[u].z); a1.y += p[u] * bhi(hb[u].z);
                a1.z += p[u] * blo(hb[u].w); a1.w += p[u] * bhi(hb[u].w);
            }
        }
        m = nm;
    }

    float4 o0, o1;
    if (deg > 0) {
        float inv = 1.f / (l + 1e-16f);
        o0.x = a0.x * inv; o0.y = a0.y * inv; o0.z = a0.z * inv; o0.w = a0.w * inv;
        o1.x = a1.x * inv; o1.y = a1.y * inv; o1.z = a1.z * inv; o1.w = a1.w * inv;
    } else {
        o0 = make_float4(0.f, 0.f, 0.f, 0.f);
        o1 = o0;
    }
    uint4 hb;
    hb.x = bpack(o0.x, o0.y); hb.y = bpack(o0.z, o0.w);
    hb.z = bpack(o1.x, o1.y); hb.w = bpack(o1.z, o1.w);
    *(uint4*)&P.hout_bf[(size_t)node * 64 + 4 * lane] = hb;
    if (P.a_s) {
        float4 b0, b1;
        b0 = *(const float4*)&P.a_s[8 * lane];
        b1 = *(const float4*)&P.a_s[8 * lane + 4];
        float vs = o0.x * b0.x + o0.y * b0.y + o0.z * b0.z + o0.w * b0.w
                 + o1.x * b1.x + o1.y * b1.y + o1.z * b1.z + o1.w * b1.w;
        b0 = *(const float4*)&P.a_d[8 * lane];
        b1 = *(const float4*)&P.a_d[8 * lane + 4];
        float vd = o0.x * b0.x + o0.y * b0.y + o0.z * b0.z + o0.w * b0.w
                 + o1.x * b1.x + o1.y * b1.y + o1.z * b1.z + o1.w * b1.w;
#pragma unroll
        for (int off = 8; off > 0; off >>= 1) {
            vs += __shfl_xor(vs, off);
            vd += __shfl_xor(vd, off);
        }
        if (lane == 0) { P.s_out[node] = vs; P.d_out[node] = vd; }
    }
}

// ---------------- fold W blocks -> transposed bf16: WeffT[64][640] ----------------
__global__ void wefft_kernel(const float* __restrict__ W, unsigned short* __restrict__ Wt) {
    int i = blockIdx.x * blockDim.x + threadIdx.x;
    if (i >= 64 * 640) return;
    int n = i / 640, k = i % 640;
    float v;
    if (k < 128)      v = W[k * 64 + n] + W[(k + 384) * 64 + n];
    else if (k < 384) v = W[k * 64 + n];
    else              v = W[(k + 128) * 64 + n];
    Wt[(size_t)n * 640 + k] = (unsigned short)(bpack(v, 0.f) & 0xFFFFu);
}

// ---------------- final dense via MFMA: out = Xcat_bf16 @ WeffT^T + b ----------------
// R21: within-panel ILP plateaued at 62us (BW 1.45 TB/s, occ 25%, 3 blk/CU).
// TLP fix (R8 lesson): 64 rows/block -> grid 1563 -> ~6 blk/CU = 24 waves/CU,
// doubling outstanding loads per CU. Wave owns ONE 16-row tile; panel-major
// order + 2-deep ping-pong preserved (FETCH stays ~63MB).
__global__ __launch_bounds__(256) void gemm_mfma(
    const unsigned* __restrict__ XBF, const unsigned* __restrict__ H1FB,
    const unsigned* __restrict__ H2FB, const unsigned* __restrict__ H1RB,
    const unsigned* __restrict__ H2RB,
    const unsigned short* __restrict__ Wt,  // [64][640] bf16
    const float* __restrict__ bias, float* __restrict__ out, int N) {
    int wid = threadIdx.x >> 6;
    int lane = threadIdx.x & 63;
    int r = lane & 15;
    int kg = lane >> 4;                   // k-group: k offset kg*8
    int rowBase = blockIdx.x * 64 + wid * 16;   // wave: ONE 16-row tile
    int arow0 = rowBase + r;
    const bool v0 = arow0 < N;
    f32x4 acc[4];
#pragma unroll
    for (int c = 0; c < 4; c++) acc[c] = (f32x4){0.f, 0.f, 0.f, 0.f};
    const bf16x8 zro = (bf16x8){0, 0, 0, 0, 0, 0, 0, 0};

#define PANEL(SRC, KOFF)                                                         \
    {                                                                            \
        const unsigned short* xs = (const unsigned short*)(SRC);                 \
        bf16x8 A0[2];                                                            \
        A0[0] = v0 ? *(const bf16x8*)(xs + (size_t)arow0 * 128 + kg * 8) : zro;  \
        _Pragma("unroll")                                                        \
        for (int tt = 0; tt < 4; ++tt) {                                         \
            if (tt < 3) {                                                        \
                int kbn = (tt + 1) * 32 + kg * 8;                                \
                A0[(tt + 1) & 1] = v0 ? *(const bf16x8*)(xs + (size_t)arow0 * 128 + kbn) : zro; \
            }                                                                    \
            int kb = tt * 32 + kg * 8;                                           \
            _Pragma("unroll")                                                    \
            for (int c = 0; c < 4; c++) {                                        \
                bf16x8 b = *(const bf16x8*)(Wt + (size_t)(c * 16 + r) * 640 + (KOFF) + kb); \
                acc[c] = __builtin_amdgcn_mfma_f32_16x16x32_bf16(A0[tt & 1], b, acc[c], 0, 0, 0); \
            }                                                                    \
        }                                                                        \
    }

    PANEL(XBF, 0)
    PANEL(H1FB, 128)
    PANEL(H2FB, 256)
    PANEL(H1RB, 384)
    PANEL(H2RB, 512)
#undef PANEL

#pragma unroll
    for (int c = 0; c < 4; c++) {
        int col = c * 16 + r;
        float bv = bias[col];
#pragma unroll
        for (int q = 0; q < 4; q++) {
            int row = rowBase + kg * 4 + q;
            if (row < N) out[(size_t)row * 64 + col] = acc[c][q] + bv;
        }
    }
}

extern "C" void kernel_launch(void* const* d_in, const int* in_sizes, int n_in,
                              void* d_out, int out_size, void* d_ws, size_t ws_size,
                              hipStream_t stream) {
    const float* feature = (const float*)d_in[0];
    const int*   eidx    = (const int*)d_in[1];
    const float* af_s    = (const float*)d_in[2];
    const float* af_d    = (const float*)d_in[3];
    const float* ar_s    = (const float*)d_in[4];
    const float* ar_d    = (const float*)d_in[5];
    const float* W       = (const float*)d_in[6];
    const float* bias    = (const float*)d_in[7];
    float* out = (float*)d_out;
    const int N = in_sizes[0] / F;
    const int E = in_sizes[1] / 2;
    const int* src = eidx;
    const int* dst = eidx + E;

    char* ws = (char*)d_ws;
    size_t off = 0;
    auto alloc = [&](size_t b) { size_t r = off; off = (off + b + 255) & ~(size_t)255; return r; };
    unsigned* xbf  = (unsigned*)(ws + alloc((size_t)N * 64 * 4));
    unsigned* h1fb = (unsigned*)(ws + alloc((size_t)N * 64 * 4));
    unsigned* h1rb = (unsigned*)(ws + alloc((size_t)N * 64 * 4));
    unsigned* h2fb = (unsigned*)(ws + alloc((size_t)N * 64 * 4));
    unsigned* h2rb = (unsigned*)(ws + alloc((size_t)N * 64 * 4));
    int*   rsF   = (int*)(ws + alloc((size_t)(N + 1) * 4));
    int*   rsR   = (int*)(ws + alloc((size_t)(N + 1) * 4));
    int*   colF  = (int*)(ws + alloc((size_t)E * 4));
    int*   colR  = (int*)(ws + alloc((size_t)E * 4));
    int*   rankF = (int*)(ws + alloc((size_t)E * 4));
    int*   rankR = (int*)(ws + alloc((size_t)E * 4));
    int*   ints2 = (int*)(ws + alloc((size_t)2 * N * 4));
    int *degF = ints2, *degR = ints2 + N;
    float* fls8 = (float*)(ws + alloc((size_t)8 * N * 4));
    float *sf = fls8, *df = fls8 + N, *sr = fls8 + 2 * (size_t)N, *dr = fls8 + 3 * (size_t)N;
    float *s2f = fls8 + 4 * (size_t)N, *d2f = fls8 + 5 * (size_t)N;
    float *s2r = fls8 + 6 * (size_t)N, *d2r = fls8 + 7 * (size_t)N;
    int*   bsums = (int*)(ws + alloc(256 * 4));
    unsigned short* WeffT = (unsigned short*)(ws + alloc(64 * 640 * 2));

    const int nb = (N + 1023) / 1024;
    zero_ints<<<(2 * N + 255) / 256, 256, 0, stream>>>(ints2, 2 * N);
    hist_kernel<<<(E + 255) / 256, 256, 0, stream>>>(src, dst, degF, degR, rankF, rankR, E);
    scan_pass1<<<dim3(nb, 2), 256, 0, stream>>>(degF, degR, rsF, rsR, bsums, N);
    scan_pass2<<<dim3(1, 2), 128, 0, stream>>>(bsums, nb);
    scan_pass3<<<dim3(nb, 2), 256, 0, stream>>>(rsF, rsR, bsums, N);
    scatter_kernel<<<(E + 255) / 256, 256, 0, stream>>>(src, dst, rsF, rsR, rankF, rankR,
                                                        colF, colR, E);
    sd4_kernel<<<(N + 3) / 4, 256, 0, stream>>>(feature, af_s, af_d, ar_s, ar_d,
                                                sf, df, sr, dr, xbf, N);

    // hop 1: gather bf16 feature (xbf), write bf16 h1 + fused next-hop dots
    AggDir F1{xbf, sf, df, rsF, colF, h1fb, af_s, af_d, s2f, d2f};
    AggDir R1{xbf, sr, dr, rsR, colR, h1rb, ar_s, ar_d, s2r, d2r};
    agg_kernel<<<dim3((N + 15) / 16, 2), 256, 0, stream>>>(F1, R1, N);
    // hop 2: gather bf16 h1, write bf16 h2
    AggDir F2{h1fb, s2f, d2f, rsF, colF, h2fb, nullptr, nullptr, nullptr, nullptr};
    AggDir R2{h1rb, s2r, d2r, rsR, colR, h2rb, nullptr, nullptr, nullptr, nullptr};
    agg_kernel<<<dim3((N + 15) / 16, 2), 256, 0, stream>>>(F2, R2, N);

    wefft_kernel<<<(64 * 640 + 255) / 256, 256, 0, stream>>>(W, WeffT);
    gemm_mfma<<<(N + 63) / 64, 256, 0, stream>>>(xbf, h1fb, h2fb, h1rb, h2rb,
                                                 WeffT, bias, out, N);
}

// Round 23
// 285.162 us; speedup vs baseline: 1.0763x; 1.0763x over previous
//
#include <hip/hip_runtime.h>
#include <math.h>

#define F 128
#define OUTDIM 64
#define NEG 0.2f

typedef __attribute__((ext_vector_type(8))) short bf16x8;
typedef __attribute__((ext_vector_type(4))) float f32x4;

// ---------------- bf16 helpers ----------------
__device__ __forceinline__ float blo(unsigned u) { return __uint_as_float(u << 16); }
__device__ __forceinline__ float bhi(unsigned u) { return __uint_as_float(u & 0xFFFF0000u); }
__device__ __forceinline__ unsigned bpack(float a, float b) {  // rtne both
    unsigned ua = __float_as_uint(a), ub = __float_as_uint(b);
    ua += 0x7FFFu + ((ua >> 16) & 1u);
    ub += 0x7FFFu + ((ub >> 16) & 1u);
    return (ua >> 16) | (ub & 0xFFFF0000u);
}

// ---------------- utility ----------------
__global__ void zero_ints(int* __restrict__ p, int n) {
    int i = blockIdx.x * blockDim.x + threadIdx.x;
    if (i < n) p[i] = 0;
}

// ---------------- CSR build ----------------
// hist records each edge's arrival rank (atomicAdd return) so scatter needs NO atomics.
__global__ void hist_kernel(const int* __restrict__ src, const int* __restrict__ dst,
                            int* __restrict__ degF, int* __restrict__ degR,
                            int* __restrict__ rankF, int* __restrict__ rankR, int E) {
    int e = blockIdx.x * blockDim.x + threadIdx.x;
    if (e < E) {
        rankF[e] = atomicAdd(&degF[dst[e]], 1);
        rankR[e] = atomicAdd(&degR[src[e]], 1);
    }
}

__global__ void scan_pass1(const int* __restrict__ degF, const int* __restrict__ degR,
                           int* __restrict__ rsF, int* __restrict__ rsR,
                           int* __restrict__ bsums, int N) {
    const int arr = blockIdx.y;
    const int* deg = arr ? degR : degF;
    int* rs = arr ? rsR : rsF;
    int tid = threadIdx.x;
    int base = blockIdx.x * 1024 + tid * 4;
    int v[4];
#pragma unroll
    for (int i = 0; i < 4; i++) v[i] = (base + i < N) ? deg[base + i] : 0;
    int s1 = v[0] + v[1] + v[2] + v[3];
    __shared__ int sd[256];
    sd[tid] = s1;
    __syncthreads();
    for (int off = 1; off < 256; off <<= 1) {
        int t = (tid >= off) ? sd[tid - off] : 0;
        __syncthreads();
        sd[tid] += t;
        __syncthreads();
    }
    int run = sd[tid] - s1;
#pragma unroll
    for (int i = 0; i < 4; i++) {
        run += v[i];
        if (base + i < N) rs[base + i + 1] = run;
    }
    if (tid == 255) bsums[arr * 128 + blockIdx.x] = sd[255];
    if (tid == 0 && blockIdx.x == 0) rs[0] = 0;
}

__global__ void scan_pass2(int* __restrict__ bsums, int nb) {
    int arr = blockIdx.y;
    int tid = threadIdx.x;  // 128
    __shared__ int sd[128];
    int v = (tid < nb) ? bsums[arr * 128 + tid] : 0;
    sd[tid] = v;
    __syncthreads();
    for (int off = 1; off < 128; off <<= 1) {
        int t = (tid >= off) ? sd[tid - off] : 0;
        __syncthreads();
        sd[tid] += t;
        __syncthreads();
    }
    bsums[arr * 128 + tid] = sd[tid];
}

__global__ void scan_pass3(int* __restrict__ rsF, int* __restrict__ rsR,
                           const int* __restrict__ bsums, int N) {
    int arr = blockIdx.y;
    if (blockIdx.x == 0) return;
    int* rs = arr ? rsR : rsF;
    int off = bsums[arr * 128 + blockIdx.x - 1];
    int base = blockIdx.x * 1024 + threadIdx.x * 4;
#pragma unroll
    for (int i = 0; i < 4; i++)
        if (base + i < N) rs[base + i + 1] += off;
}

// atomic-free: position = rs[node] + precomputed rank
__global__ void scatter_kernel(const int* __restrict__ src, const int* __restrict__ dst,
                               const int* __restrict__ rsF, const int* __restrict__ rsR,
                               const int* __restrict__ rankF, const int* __restrict__ rankR,
                               int* __restrict__ colF, int* __restrict__ colR, int E) {
    int e = blockIdx.x * blockDim.x + threadIdx.x;
    if (e < E) {
        int s = src[e], d = dst[e];
        colF[rsF[d] + rankF[e]] = s;
        colR[rsR[s] + rankR[e]] = d;
    }
}

// ---------------- per-node attention scalars + bf16 feature copy ----------------
__global__ void sd4_kernel(const float* __restrict__ x,
                           const float* __restrict__ af_s, const float* __restrict__ af_d,
                           const float* __restrict__ ar_s, const float* __restrict__ ar_d,
                           float* __restrict__ sf, float* __restrict__ df,
                           float* __restrict__ sr, float* __restrict__ dr,
                           unsigned* __restrict__ xbf, int N) {
    int node = blockIdx.x * 4 + (threadIdx.x >> 6);
    int lane = threadIdx.x & 63;
    if (node >= N) return;
    const float2 xv = *(const float2*)&x[(size_t)node * F + 2 * lane];
    xbf[(size_t)node * 64 + lane] = bpack(xv.x, xv.y);
    float2 a;
    a = *(const float2*)&af_s[2 * lane]; float vsf = xv.x * a.x + xv.y * a.y;
    a = *(const float2*)&af_d[2 * lane]; float vdf = xv.x * a.x + xv.y * a.y;
    a = *(const float2*)&ar_s[2 * lane]; float vsr = xv.x * a.x + xv.y * a.y;
    a = *(const float2*)&ar_d[2 * lane]; float vdr = xv.x * a.x + xv.y * a.y;
#pragma unroll
    for (int off = 32; off > 0; off >>= 1) {
        vsf += __shfl_xor(vsf, off);
        vdf += __shfl_xor(vdf, off);
        vsr += __shfl_xor(vsr, off);
        vdr += __shfl_xor(vdr, off);
    }
    if (lane == 0) { sf[node] = vsf; df[node] = vdf; sr[node] = vsr; dr[node] = vdr; }
}

// ---------------- fused dual-direction attention hop ----------------
// quarter-wave (16 lanes) per node; blockIdx.y selects direction.
// bf16 rows (256 B), 8-deep gather pipeline (raw uint4 staging).
struct AggDir {
    const unsigned* hin_bf;  // [N][64]  bf16x2
    const float* s;          // [N]
    const float* d;          // [N]
    const int* rs;           // [N+1]
    const int* col;          // [E]
    unsigned* hout_bf;       // [N][64]  bf16x2
    const float* a_s;        // nullable: fused next-hop dots
    const float* a_d;
    float* s_out;
    float* d_out;
};

__global__ __launch_bounds__(256) void agg_kernel(AggDir D0, AggDir D1, int N) {
    AggDir P = blockIdx.y ? D1 : D0;
    int node = blockIdx.x * 16 + (threadIdx.x >> 4);
    int lane = threadIdx.x & 15;           // within quarter-wave
    int qbase = threadIdx.x & 48;          // quarter offset inside the wave
    if (node >= N) return;
    float di = P.d[node];
    int beg = P.rs[node], end = P.rs[node + 1];
    int deg = end - beg;
    float m = -INFINITY, l = 0.f;
    float4 a0 = make_float4(0.f, 0.f, 0.f, 0.f);
    float4 a1 = make_float4(0.f, 0.f, 0.f, 0.f);

    for (int base = 0; base < deg; base += 16) {
        int cnt = min(16, deg - base);
        int sj_l = 0;
        float e_l = -INFINITY;
        if (lane < cnt) {
            sj_l = P.col[beg + base + lane];
            float e = P.s[sj_l] + di;
            e_l = (e >= 0.f) ? e : NEG * e;
        }
        float bm = e_l;
#pragma unroll
        for (int off = 8; off > 0; off >>= 1) bm = fmaxf(bm, __shfl_xor(bm, off));
        float nm = fmaxf(m, bm);
        float p_l = (lane < cnt) ? __expf(e_l - nm) : 0.f;
        float ps = p_l;
#pragma unroll
        for (int off = 8; off > 0; off >>= 1) ps += __shfl_xor(ps, off);
        float sc = (m == -INFINITY) ? 0.f : __expf(m - nm);
        l = l * sc + ps;
        a0.x *= sc; a0.y *= sc; a0.z *= sc; a0.w *= sc;
        a1.x *= sc; a1.y *= sc; a1.z *= sc; a1.w *= sc;
        // 8-deep gather: stage raw bf16x2 lines (uint4), convert at FMA time
        for (int j0 = 0; j0 < cnt; j0 += 8) {
            int sj[8]; float p[8]; uint4 hb[8];
#pragma unroll
            for (int u = 0; u < 8; u++) {
                sj[u] = __shfl(sj_l, qbase + j0 + u);
                p[u]  = __shfl(p_l,  qbase + j0 + u);
            }
#pragma unroll
            for (int u = 0; u < 8; u++) {
                if (j0 + u < cnt) {  // uniform per quarter-wave
                    hb[u] = *(const uint4*)&P.hin_bf[(size_t)sj[u] * 64 + 4 * lane];
                } else {
                    hb[u] = make_uint4(0u, 0u, 0u, 0u);
                }
            }
#pragma unroll
            for (int u = 0; u < 8; u++) {
                a0.x += p[u] * blo(hb[u].x); a0.y += p[u] * bhi(hb[u].x);
                a0.z += p[u] * blo(hb[u].y); a0.w += p[u] * bhi(hb[u].y);
                a1.x += p[u] * blo(hb[u].z); a1.y += p[u] * bhi(hb[u].z);
                a1.z += p[u] * blo(hb[u].w); a1.w += p[u] * bhi(hb[u].w);
            }
        }
        m = nm;
    }

    float4 o0, o1;
    if (deg > 0) {
        float inv = 1.f / (l + 1e-16f);
        o0.x = a0.x * inv; o0.y = a0.y * inv; o0.z = a0.z * inv; o0.w = a0.w * inv;
        o1.x = a1.x * inv; o1.y = a1.y * inv; o1.z = a1.z * inv; o1.w = a1.w * inv;
    } else {
        o0 = make_float4(0.f, 0.f, 0.f, 0.f);
        o1 = o0;
    }
    uint4 hb;
    hb.x = bpack(o0.x, o0.y); hb.y = bpack(o0.z, o0.w);
    hb.z = bpack(o1.x, o1.y); hb.w = bpack(o1.z, o1.w);
    *(uint4*)&P.hout_bf[(size_t)node * 64 + 4 * lane] = hb;
    if (P.a_s) {
        float4 b0, b1;
        b0 = *(const float4*)&P.a_s[8 * lane];
        b1 = *(const float4*)&P.a_s[8 * lane + 4];
        float vs = o0.x * b0.x + o0.y * b0.y + o0.z * b0.z + o0.w * b0.w
                 + o1.x * b1.x + o1.y * b1.y + o1.z * b1.z + o1.w * b1.w;
        b0 = *(const float4*)&P.a_d[8 * lane];
        b1 = *(const float4*)&P.a_d[8 * lane + 4];
        float vd = o0.x * b0.x + o0.y * b0.y + o0.z * b0.z + o0.w * b0.w
                 + o1.x * b1.x + o1.y * b1.y + o1.z * b1.z + o1.w * b1.w;
#pragma unroll
        for (int off = 8; off > 0; off >>= 1) {
            vs += __shfl_xor(vs, off);
            vd += __shfl_xor(vd, off);
        }
        if (lane == 0) { P.s_out[node] = vs; P.d_out[node] = vd; }
    }
}

// ---------------- fold W blocks -> transposed bf16: WeffT[64][640] ----------------
__global__ void wefft_kernel(const float* __restrict__ W, unsigned short* __restrict__ Wt) {
    int i = blockIdx.x * blockDim.x + threadIdx.x;
    if (i >= 64 * 640) return;
    int n = i / 640, k = i % 640;
    float v;
    if (k < 128)      v = W[k * 64 + n] + W[(k + 384) * 64 + n];
    else if (k < 384) v = W[k * 64 + n];
    else              v = W[(k + 128) * 64 + n];
    Wt[(size_t)n * 640 + k] = (unsigned short)(bpack(v, 0.f) & 0xFFFFu);
}

// ---------------- final dense via MFMA: out = Xcat_bf16 @ WeffT^T + b ----------------
// R22 diagnosis: ~7400 cyc/k-step -- the b-fragment was loaded IMMEDIATELY
// before its MFMA (4 dependent latency hops per k-step; TLP can't hide it).
// Fix: double-buffer BOTH A and B -- issue all 6 of step tt+1's independent
// loads before step tt's 8 MFMAs. [tt&1] indices under full unroll (rule #20).
// Shape: R21's 2 row-tiles / 128 rows per 256-thr block, panel-major.
__global__ __launch_bounds__(256) void gemm_mfma(
    const unsigned* __restrict__ XBF, const unsigned* __restrict__ H1FB,
    const unsigned* __restrict__ H2FB, const unsigned* __restrict__ H1RB,
    const unsigned* __restrict__ H2RB,
    const unsigned short* __restrict__ Wt,  // [64][640] bf16
    const float* __restrict__ bias, float* __restrict__ out, int N) {
    int wid = threadIdx.x >> 6;
    int lane = threadIdx.x & 63;
    int r = lane & 15;
    int kg = lane >> 4;                   // k-group: k offset kg*8
    int rowBase = blockIdx.x * 128 + wid * 32;  // wave: 2 row-tiles of 16
    int arow0 = rowBase + r;
    int arow1 = rowBase + 16 + r;
    const bool v0 = arow0 < N, v1 = arow1 < N;
    f32x4 acc[2][4];
#pragma unroll
    for (int m = 0; m < 2; m++)
#pragma unroll
        for (int c = 0; c < 4; c++) acc[m][c] = (f32x4){0.f, 0.f, 0.f, 0.f};
    const bf16x8 zro = (bf16x8){0, 0, 0, 0, 0, 0, 0, 0};

#define PANEL(SRC, KOFF)                                                         \
    {                                                                            \
        const unsigned short* xs = (const unsigned short*)(SRC);                 \
        bf16x8 A0[2], A1[2], B[2][4];                                            \
        {                                                                        \
            int kb = kg * 8;                                                     \
            A0[0] = v0 ? *(const bf16x8*)(xs + (size_t)arow0 * 128 + kb) : zro;  \
            A1[0] = v1 ? *(const bf16x8*)(xs + (size_t)arow1 * 128 + kb) : zro;  \
            _Pragma("unroll")                                                    \
            for (int c = 0; c < 4; c++)                                          \
                B[0][c] = *(const bf16x8*)(Wt + (size_t)(c * 16 + r) * 640 + (KOFF) + kb); \
        }                                                                        \
        _Pragma("unroll")                                                        \
        for (int tt = 0; tt < 4; ++tt) {                                         \
            if (tt < 3) {                                                        \
                int kbn = (tt + 1) * 32 + kg * 8;                                \
                A0[(tt + 1) & 1] = v0 ? *(const bf16x8*)(xs + (size_t)arow0 * 128 + kbn) : zro; \
                A1[(tt + 1) & 1] = v1 ? *(const bf16x8*)(xs + (size_t)arow1 * 128 + kbn) : zro; \
                _Pragma("unroll")                                                \
                for (int c = 0; c < 4; c++)                                      \
                    B[(tt + 1) & 1][c] = *(const bf16x8*)(Wt + (size_t)(c * 16 + r) * 640 + (KOFF) + kbn); \
            }                                                                    \
            _Pragma("unroll")                                                    \
            for (int c = 0; c < 4; c++) {                                        \
                acc[0][c] = __builtin_amdgcn_mfma_f32_16x16x32_bf16(A0[tt & 1], B[tt & 1][c], acc[0][c], 0, 0, 0); \
                acc[1][c] = __builtin_amdgcn_mfma_f32_16x16x32_bf16(A1[tt & 1], B[tt & 1][c], acc[1][c], 0, 0, 0); \
            }                                                                    \
        }                                                                        \
    }

    PANEL(XBF, 0)
    PANEL(H1FB, 128)
    PANEL(H2FB, 256)
    PANEL(H1RB, 384)
    PANEL(H2RB, 512)
#undef PANEL

#pragma unroll
    for (int m = 0; m < 2; m++)
#pragma unroll
        for (int c = 0; c < 4; c++) {
            int col = c * 16 + r;
            float bv = bias[col];
#pragma unroll
            for (int q = 0; q < 4; q++) {
                int row = rowBase + m * 16 + kg * 4 + q;
                if (row < N) out[(size_t)row * 64 + col] = acc[m][c][q] + bv;
            }
        }
}

extern "C" void kernel_launch(void* const* d_in, const int* in_sizes, int n_in,
                              void* d_out, int out_size, void* d_ws, size_t ws_size,
                              hipStream_t stream) {
    const float* feature = (const float*)d_in[0];
    const int*   eidx    = (const int*)d_in[1];
    const float* af_s    = (const float*)d_in[2];
    const float* af_d    = (const float*)d_in[3];
    const float* ar_s    = (const float*)d_in[4];
    const float* ar_d    = (const float*)d_in[5];
    const float* W       = (const float*)d_in[6];
    const float* bias    = (const float*)d_in[7];
    float* out = (float*)d_out;
    const int N = in_sizes[0] / F;
    const int E = in_sizes[1] / 2;
    const int* src = eidx;
    const int* dst = eidx + E;

    char* ws = (char*)d_ws;
    size_t off = 0;
    auto alloc = [&](size_t b) { size_t r = off; off = (off + b + 255) & ~(size_t)255; return r; };
    unsigned* xbf  = (unsigned*)(ws + alloc((size_t)N * 64 * 4));
    unsigned* h1fb = (unsigned*)(ws + alloc((size_t)N * 64 * 4));
    unsigned* h1rb = (unsigned*)(ws + alloc((size_t)N * 64 * 4));
    unsigned* h2fb = (unsigned*)(ws + alloc((size_t)N * 64 * 4));
    unsigned* h2rb = (unsigned*)(ws + alloc((size_t)N * 64 * 4));
    int*   rsF   = (int*)(ws + alloc((size_t)(N + 1) * 4));
    int*   rsR   = (int*)(ws + alloc((size_t)(N + 1) * 4));
    int*   colF  = (int*)(ws + alloc((size_t)E * 4));
    int*   colR  = (int*)(ws + alloc((size_t)E * 4));
    int*   rankF = (int*)(ws + alloc((size_t)E * 4));
    int*   rankR = (int*)(ws + alloc((size_t)E * 4));
    int*   ints2 = (int*)(ws + alloc((size_t)2 * N * 4));
    int *degF = ints2, *degR = ints2 + N;
    float* fls8 = (float*)(ws + alloc((size_t)8 * N * 4));
    float *sf = fls8, *df = fls8 + N, *sr = fls8 + 2 * (size_t)N, *dr = fls8 + 3 * (size_t)N;
    float *s2f = fls8 + 4 * (size_t)N, *d2f = fls8 + 5 * (size_t)N;
    float *s2r = fls8 + 6 * (size_t)N, *d2r = fls8 + 7 * (size_t)N;
    int*   bsums = (int*)(ws + alloc(256 * 4));
    unsigned short* WeffT = (unsigned short*)(ws + alloc(64 * 640 * 2));

    const int nb = (N + 1023) / 1024;
    zero_ints<<<(2 * N + 255) / 256, 256, 0, stream>>>(ints2, 2 * N);
    hist_kernel<<<(E + 255) / 256, 256, 0, stream>>>(src, dst, degF, degR, rankF, rankR, E);
    scan_pass1<<<dim3(nb, 2), 256, 0, stream>>>(degF, degR, rsF, rsR, bsums, N);
    scan_pass2<<<dim3(1, 2), 128, 0, stream>>>(bsums, nb);
    scan_pass3<<<dim3(nb, 2), 256, 0, stream>>>(rsF, rsR, bsums, N);
    scatter_kernel<<<(E + 255) / 256, 256, 0, stream>>>(src, dst, rsF, rsR, rankF, rankR,
                                                        colF, colR, E);
    sd4_kernel<<<(N + 3) / 4, 256, 0, stream>>>(feature, af_s, af_d, ar_s, ar_d,
                                                sf, df, sr, dr, xbf, N);

    // hop 1: gather bf16 feature (xbf), write bf16 h1 + fused next-hop dots
    AggDir F1{xbf, sf, df, rsF, colF, h1fb, af_s, af_d, s2f, d2f};
    AggDir R1{xbf, sr, dr, rsR, colR, h1rb, ar_s, ar_d, s2r, d2r};
    agg_kernel<<<dim3((N + 15) / 16, 2), 256, 0, stream>>>(F1, R1, N);
    // hop 2: gather bf16 h1, write bf16 h2
    AggDir F2{h1fb, s2f, d2f, rsF, colF, h2fb, nullptr, nullptr, nullptr, nullptr};
    AggDir R2{h1rb, s2r, d2r, rsR, colR, h2rb, nullptr, nullptr, nullptr, nullptr};
    agg_kernel<<<dim3((N + 15) / 16, 2), 256, 0, stream>>>(F2, R2, N);

    wefft_kernel<<<(64 * 640 + 255) / 256, 256, 0, stream>>>(W, WeffT);
    gemm_mfma<<<(N + 127) / 128, 256, 0, stream>>>(xbf, h1fb, h2fb, h1rb, h2rb,
                                                   WeffT, bias, out, N);
}

// Round 24
// 284.439 us; speedup vs baseline: 1.0790x; 1.0025x over previous
//
#include <hip/hip_runtime.h>
#include <math.h>

#define F 128
#define OUTDIM 64
#define NEG 0.2f

typedef __attribute__((ext_vector_type(8))) short bf16x8;
typedef __attribute__((ext_vector_type(4))) float f32x4;

// ---------------- bf16 helpers ----------------
__device__ __forceinline__ float blo(unsigned u) { return __uint_as_float(u << 16); }
__device__ __forceinline__ float bhi(unsigned u) { return __uint_as_float(u & 0xFFFF0000u); }
__device__ __forceinline__ unsigned bpack(float a, float b) {  // rtne both
    unsigned ua = __float_as_uint(a), ub = __float_as_uint(b);
    ua += 0x7FFFu + ((ua >> 16) & 1u);
    ub += 0x7FFFu + ((ub >> 16) & 1u);
    return (ua >> 16) | (ub & 0xFFFF0000u);
}

// ---------------- utility ----------------
__global__ void zero_ints(int* __restrict__ p, int n) {
    int i = blockIdx.x * blockDim.x + threadIdx.x;
    if (i < n) p[i] = 0;
}

// ---------------- CSR build ----------------
// hist records each edge's arrival rank (atomicAdd return) so scatter needs NO atomics.
__global__ void hist_kernel(const int* __restrict__ src, const int* __restrict__ dst,
                            int* __restrict__ degF, int* __restrict__ degR,
                            int* __restrict__ rankF, int* __restrict__ rankR, int E) {
    int e = blockIdx.x * blockDim.x + threadIdx.x;
    if (e < E) {
        rankF[e] = atomicAdd(&degF[dst[e]], 1);
        rankR[e] = atomicAdd(&degR[src[e]], 1);
    }
}

__global__ void scan_pass1(const int* __restrict__ degF, const int* __restrict__ degR,
                           int* __restrict__ rsF, int* __restrict__ rsR,
                           int* __restrict__ bsums, int N) {
    const int arr = blockIdx.y;
    const int* deg = arr ? degR : degF;
    int* rs = arr ? rsR : rsF;
    int tid = threadIdx.x;
    int base = blockIdx.x * 1024 + tid * 4;
    int v[4];
#pragma unroll
    for (int i = 0; i < 4; i++) v[i] = (base + i < N) ? deg[base + i] : 0;
    int s1 = v[0] + v[1] + v[2] + v[3];
    __shared__ int sd[256];
    sd[tid] = s1;
    __syncthreads();
    for (int off = 1; off < 256; off <<= 1) {
        int t = (tid >= off) ? sd[tid - off] : 0;
        __syncthreads();
        sd[tid] += t;
        __syncthreads();
    }
    int run = sd[tid] - s1;
#pragma unroll
    for (int i = 0; i < 4; i++) {
        run += v[i];
        if (base + i < N) rs[base + i + 1] = run;
    }
    if (tid == 255) bsums[arr * 128 + blockIdx.x] = sd[255];
    if (tid == 0 && blockIdx.x == 0) rs[0] = 0;
}

__global__ void scan_pass2(int* __restrict__ bsums, int nb) {
    int arr = blockIdx.y;
    int tid = threadIdx.x;  // 128
    __shared__ int sd[128];
    int v = (tid < nb) ? bsums[arr * 128 + tid] : 0;
    sd[tid] = v;
    __syncthreads();
    for (int off = 1; off < 128; off <<= 1) {
        int t = (tid >= off) ? sd[tid - off] : 0;
        __syncthreads();
        sd[tid] += t;
        __syncthreads();
    }
    bsums[arr * 128 + tid] = sd[tid];
}

__global__ void scan_pass3(int* __restrict__ rsF, int* __restrict__ rsR,
                           const int* __restrict__ bsums, int N) {
    int arr = blockIdx.y;
    if (blockIdx.x == 0) return;
    int* rs = arr ? rsR : rsF;
    int off = bsums[arr * 128 + blockIdx.x - 1];
    int base = blockIdx.x * 1024 + threadIdx.x * 4;
#pragma unroll
    for (int i = 0; i < 4; i++)
        if (base + i < N) rs[base + i + 1] += off;
}

// atomic-free: position = rs[node] + precomputed rank
__global__ void scatter_kernel(const int* __restrict__ src, const int* __restrict__ dst,
                               const int* __restrict__ rsF, const int* __restrict__ rsR,
                               const int* __restrict__ rankF, const int* __restrict__ rankR,
                               int* __restrict__ colF, int* __restrict__ colR, int E) {
    int e = blockIdx.x * blockDim.x + threadIdx.x;
    if (e < E) {
        int s = src[e], d = dst[e];
        colF[rsF[d] + rankF[e]] = s;
        colR[rsR[s] + rankR[e]] = d;
    }
}

// ---------------- per-node attention scalars + bf16 feature copy ----------------
__global__ void sd4_kernel(const float* __restrict__ x,
                           const float* __restrict__ af_s, const float* __restrict__ af_d,
                           const float* __restrict__ ar_s, const float* __restrict__ ar_d,
                           float* __restrict__ sf, float* __restrict__ df,
                           float* __restrict__ sr, float* __restrict__ dr,
                           unsigned* __restrict__ xbf, int N) {
    int node = blockIdx.x * 4 + (threadIdx.x >> 6);
    int lane = threadIdx.x & 63;
    if (node >= N) return;
    const float2 xv = *(const float2*)&x[(size_t)node * F + 2 * lane];
    xbf[(size_t)node * 64 + lane] = bpack(xv.x, xv.y);
    float2 a;
    a = *(const float2*)&af_s[2 * lane]; float vsf = xv.x * a.x + xv.y * a.y;
    a = *(const float2*)&af_d[2 * lane]; float vdf = xv.x * a.x + xv.y * a.y;
    a = *(const float2*)&ar_s[2 * lane]; float vsr = xv.x * a.x + xv.y * a.y;
    a = *(const float2*)&ar_d[2 * lane]; float vdr = xv.x * a.x + xv.y * a.y;
#pragma unroll
    for (int off = 32; off > 0; off >>= 1) {
        vsf += __shfl_xor(vsf, off);
        vdf += __shfl_xor(vdf, off);
        vsr += __shfl_xor(vsr, off);
        vdr += __shfl_xor(vdr, off);
    }
    if (lane == 0) { sf[node] = vsf; df[node] = vdf; sr[node] = vsr; dr[node] = vdr; }
}

// ---------------- fused dual-direction attention hop ----------------
// quarter-wave (16 lanes) per node; blockIdx.y selects direction.
// bf16 rows (256 B), 8-deep gather pipeline (raw uint4 staging).
struct AggDir {
    const unsigned* hin_bf;  // [N][64]  bf16x2
    const float* s;          // [N]
    const float* d;          // [N]
    const int* rs;           // [N+1]
    const int* col;          // [E]
    unsigned* hout_bf;       // [N][64]  bf16x2
    const float* a_s;        // nullable: fused next-hop dots
    const float* a_d;
    float* s_out;
    float* d_out;
};

__global__ __launch_bounds__(256) void agg_kernel(AggDir D0, AggDir D1, int N) {
    AggDir P = blockIdx.y ? D1 : D0;
    int node = blockIdx.x * 16 + (threadIdx.x >> 4);
    int lane = threadIdx.x & 15;           // within quarter-wave
    int qbase = threadIdx.x & 48;          // quarter offset inside the wave
    if (node >= N) return;
    float di = P.d[node];
    int beg = P.rs[node], end = P.rs[node + 1];
    int deg = end - beg;
    float m = -INFINITY, l = 0.f;
    float4 a0 = make_float4(0.f, 0.f, 0.f, 0.f);
    float4 a1 = make_float4(0.f, 0.f, 0.f, 0.f);

    for (int base = 0; base < deg; base += 16) {
        int cnt = min(16, deg - base);
        int sj_l = 0;
        float e_l = -INFINITY;
        if (lane < cnt) {
            sj_l = P.col[beg + base + lane];
            float e = P.s[sj_l] + di;
            e_l = (e >= 0.f) ? e : NEG * e;
        }
        float bm = e_l;
#pragma unroll
        for (int off = 8; off > 0; off >>= 1) bm = fmaxf(bm, __shfl_xor(bm, off));
        float nm = fmaxf(m, bm);
        float p_l = (lane < cnt) ? __expf(e_l - nm) : 0.f;
        float ps = p_l;
#pragma unroll
        for (int off = 8; off > 0; off >>= 1) ps += __shfl_xor(ps, off);
        float sc = (m == -INFINITY) ? 0.f : __expf(m - nm);
        l = l * sc + ps;
        a0.x *= sc; a0.y *= sc; a0.z *= sc; a0.w *= sc;
        a1.x *= sc; a1.y *= sc; a1.z *= sc; a1.w *= sc;
        // 8-deep gather: stage raw bf16x2 lines (uint4), convert at FMA time
        for (int j0 = 0; j0 < cnt; j0 += 8) {
            int sj[8]; float p[8]; uint4 hb[8];
#pragma unroll
            for (int u = 0; u < 8; u++) {
                sj[u] = __shfl(sj_l, qbase + j0 + u);
                p[u]  = __shfl(p_l,  qbase + j0 + u);
            }
#pragma unroll
            for (int u = 0; u < 8; u++) {
                if (j0 + u < cnt) {  // uniform per quarter-wave
                    hb[u] = *(const uint4*)&P.hin_bf[(size_t)sj[u] * 64 + 4 * lane];
                } else {
                    hb[u] = make_uint4(0u, 0u, 0u, 0u);
                }
            }
#pragma unroll
            for (int u = 0; u < 8; u++) {
                a0.x += p[u] * blo(hb[u].x); a0.y += p[u] * bhi(hb[u].x);
                a0.z += p[u] * blo(hb[u].y); a0.w += p[u] * bhi(hb[u].y);
                a1.x += p[u] * blo(hb[u].z); a1.y += p[u] * bhi(hb[u].z);
                a1.z += p[u] * blo(hb[u].w); a1.w += p[u] * bhi(hb[u].w);
            }
        }
        m = nm;
    }

    float4 o0, o1;
    if (deg > 0) {
        float inv = 1.f / (l + 1e-16f);
        o0.x = a0.x * inv; o0.y = a0.y * inv; o0.z = a0.z * inv; o0.w = a0.w * inv;
        o1.x = a1.x * inv; o1.y = a1.y * inv; o1.z = a1.z * inv; o1.w = a1.w * inv;
    } else {
        o0 = make_float4(0.f, 0.f, 0.f, 0.f);
        o1 = o0;
    }
    uint4 hb;
    hb.x = bpack(o0.x, o0.y); hb.y = bpack(o0.z, o0.w);
    hb.z = bpack(o1.x, o1.y); hb.w = bpack(o1.z, o1.w);
    *(uint4*)&P.hout_bf[(size_t)node * 64 + 4 * lane] = hb;
    if (P.a_s) {
        float4 b0, b1;
        b0 = *(const float4*)&P.a_s[8 * lane];
        b1 = *(const float4*)&P.a_s[8 * lane + 4];
        float vs = o0.x * b0.x + o0.y * b0.y + o0.z * b0.z + o0.w * b0.w
                 + o1.x * b1.x + o1.y * b1.y + o1.z * b1.z + o1.w * b1.w;
        b0 = *(const float4*)&P.a_d[8 * lane];
        b1 = *(const float4*)&P.a_d[8 * lane + 4];
        float vd = o0.x * b0.x + o0.y * b0.y + o0.z * b0.z + o0.w * b0.w
                 + o1.x * b1.x + o1.y * b1.y + o1.z * b1.z + o1.w * b1.w;
#pragma unroll
        for (int off = 8; off > 0; off >>= 1) {
            vs += __shfl_xor(vs, off);
            vd += __shfl_xor(vd, off);
        }
        if (lane == 0) { P.s_out[node] = vs; P.d_out[node] = vd; }
    }
}

// ---------------- fold W blocks -> transposed bf16: WeffT[64][640] ----------------
__global__ void wefft_kernel(const float* __restrict__ W, unsigned short* __restrict__ Wt) {
    int i = blockIdx.x * blockDim.x + threadIdx.x;
    if (i >= 64 * 640) return;
    int n = i / 640, k = i % 640;
    float v;
    if (k < 128)      v = W[k * 64 + n] + W[(k + 384) * 64 + n];
    else if (k < 384) v = W[k * 64 + n];
    else              v = W[(k + 128) * 64 + n];
    Wt[(size_t)n * 640 + k] = (unsigned short)(bpack(v, 0.f) & 0xFFFFu);
}

// ---------------- final dense via MFMA: out = Xcat_bf16 @ WeffT^T + b ----------------
// R19/R21/R23 all pinned at 62us with pipeline depth ~2: each k-step's loads
// stall ~900cyc (half of A misses to HBM per FETCH=63MB) that 8 MFMAs can't
// cover. Agg kernels sustain 3-4 TB/s by batch-issuing many independent
// loads; apply same pattern: per panel, prefetch ALL 8 A + 16 B fragments
// (24 independent loads in flight), then run the 32 MFMAs. ~160 VGPR ->
// 2 waves/SIMD, 8 waves x 24 loads = 192 outstanding/CU.
__global__ __launch_bounds__(256) void gemm_mfma(
    const unsigned* __restrict__ XBF, const unsigned* __restrict__ H1FB,
    const unsigned* __restrict__ H2FB, const unsigned* __restrict__ H1RB,
    const unsigned* __restrict__ H2RB,
    const unsigned short* __restrict__ Wt,  // [64][640] bf16
    const float* __restrict__ bias, float* __restrict__ out, int N) {
    int wid = threadIdx.x >> 6;
    int lane = threadIdx.x & 63;
    int r = lane & 15;
    int kg = lane >> 4;                   // k-group: k offset kg*8
    int rowBase = blockIdx.x * 128 + wid * 32;  // wave: 2 row-tiles of 16
    int arow0 = rowBase + r;
    int arow1 = rowBase + 16 + r;
    const bool v0 = arow0 < N, v1 = arow1 < N;
    f32x4 acc[2][4];
#pragma unroll
    for (int m = 0; m < 2; m++)
#pragma unroll
        for (int c = 0; c < 4; c++) acc[m][c] = (f32x4){0.f, 0.f, 0.f, 0.f};
    const bf16x8 zro = (bf16x8){0, 0, 0, 0, 0, 0, 0, 0};

#define PANEL(SRC, KOFF)                                                         \
    {                                                                            \
        const unsigned short* xs = (const unsigned short*)(SRC);                 \
        bf16x8 A0[4], A1[4], B[4][4];                                            \
        _Pragma("unroll")                                                        \
        for (int tt = 0; tt < 4; ++tt) {                                         \
            int kb = tt * 32 + kg * 8;                                           \
            A0[tt] = v0 ? *(const bf16x8*)(xs + (size_t)arow0 * 128 + kb) : zro; \
            A1[tt] = v1 ? *(const bf16x8*)(xs + (size_t)arow1 * 128 + kb) : zro; \
            _Pragma("unroll")                                                    \
            for (int c = 0; c < 4; c++)                                          \
                B[tt][c] = *(const bf16x8*)(Wt + (size_t)(c * 16 + r) * 640 + (KOFF) + kb); \
        }                                                                        \
        _Pragma("unroll")                                                        \
        for (int tt = 0; tt < 4; ++tt) {                                         \
            _Pragma("unroll")                                                    \
            for (int c = 0; c < 4; c++) {                                        \
                acc[0][c] = __builtin_amdgcn_mfma_f32_16x16x32_bf16(A0[tt], B[tt][c], acc[0][c], 0, 0, 0); \
                acc[1][c] = __builtin_amdgcn_mfma_f32_16x16x32_bf16(A1[tt], B[tt][c], acc[1][c], 0, 0, 0); \
            }                                                                    \
        }                                                                        \
    }

    PANEL(XBF, 0)
    PANEL(H1FB, 128)
    PANEL(H2FB, 256)
    PANEL(H1RB, 384)
    PANEL(H2RB, 512)
#undef PANEL

#pragma unroll
    for (int m = 0; m < 2; m++)
#pragma unroll
        for (int c = 0; c < 4; c++) {
            int col = c * 16 + r;
            float bv = bias[col];
#pragma unroll
            for (int q = 0; q < 4; q++) {
                int row = rowBase + m * 16 + kg * 4 + q;
                if (row < N) out[(size_t)row * 64 + col] = acc[m][c][q] + bv;
            }
        }
}

extern "C" void kernel_launch(void* const* d_in, const int* in_sizes, int n_in,
                              void* d_out, int out_size, void* d_ws, size_t ws_size,
                              hipStream_t stream) {
    const float* feature = (const float*)d_in[0];
    const int*   eidx    = (const int*)d_in[1];
    const float* af_s    = (const float*)d_in[2];
    const float* af_d    = (const float*)d_in[3];
    const float* ar_s    = (const float*)d_in[4];
    const float* ar_d    = (const float*)d_in[5];
    const float* W       = (const float*)d_in[6];
    const float* bias    = (const float*)d_in[7];
    float* out = (float*)d_out;
    const int N = in_sizes[0] / F;
    const int E = in_sizes[1] / 2;
    const int* src = eidx;
    const int* dst = eidx + E;

    char* ws = (char*)d_ws;
    size_t off = 0;
    auto alloc = [&](size_t b) { size_t r = off; off = (off + b + 255) & ~(size_t)255; return r; };
    unsigned* xbf  = (unsigned*)(ws + alloc((size_t)N * 64 * 4));
    unsigned* h1fb = (unsigned*)(ws + alloc((size_t)N * 64 * 4));
    unsigned* h1rb = (unsigned*)(ws + alloc((size_t)N * 64 * 4));
    unsigned* h2fb = (unsigned*)(ws + alloc((size_t)N * 64 * 4));
    unsigned* h2rb = (unsigned*)(ws + alloc((size_t)N * 64 * 4));
    int*   rsF   = (int*)(ws + alloc((size_t)(N + 1) * 4));
    int*   rsR   = (int*)(ws + alloc((size_t)(N + 1) * 4));
    int*   colF  = (int*)(ws + alloc((size_t)E * 4));
    int*   colR  = (int*)(ws + alloc((size_t)E * 4));
    int*   rankF = (int*)(ws + alloc((size_t)E * 4));
    int*   rankR = (int*)(ws + alloc((size_t)E * 4));
    int*   ints2 = (int*)(ws + alloc((size_t)2 * N * 4));
    int *degF = ints2, *degR = ints2 + N;
    float* fls8 = (float*)(ws + alloc((size_t)8 * N * 4));
    float *sf = fls8, *df = fls8 + N, *sr = fls8 + 2 * (size_t)N, *dr = fls8 + 3 * (size_t)N;
    float *s2f = fls8 + 4 * (size_t)N, *d2f = fls8 + 5 * (size_t)N;
    float *s2r = fls8 + 6 * (size_t)N, *d2r = fls8 + 7 * (size_t)N;
    int*   bsums = (int*)(ws + alloc(256 * 4));
    unsigned short* WeffT = (unsigned short*)(ws + alloc(64 * 640 * 2));

    const int nb = (N + 1023) / 1024;
    zero_ints<<<(2 * N + 255) / 256, 256, 0, stream>>>(ints2, 2 * N);
    hist_kernel<<<(E + 255) / 256, 256, 0, stream>>>(src, dst, degF, degR, rankF, rankR, E);
    scan_pass1<<<dim3(nb, 2), 256, 0, stream>>>(degF, degR, rsF, rsR, bsums, N);
    scan_pass2<<<dim3(1, 2), 128, 0, stream>>>(bsums, nb);
    scan_pass3<<<dim3(nb, 2), 256, 0, stream>>>(rsF, rsR, bsums, N);
    scatter_kernel<<<(E + 255) / 256, 256, 0, stream>>>(src, dst, rsF, rsR, rankF, rankR,
                                                        colF, colR, E);
    sd4_kernel<<<(N + 3) / 4, 256, 0, stream>>>(feature, af_s, af_d, ar_s, ar_d,
                                                sf, df, sr, dr, xbf, N);

    // hop 1: gather bf16 feature (xbf), write bf16 h1 + fused next-hop dots
    AggDir F1{xbf, sf, df, rsF, colF, h1fb, af_s, af_d, s2f, d2f};
    AggDir R1{xbf, sr, dr, rsR, colR, h1rb, ar_s, ar_d, s2r, d2r};
    agg_kernel<<<dim3((N + 15) / 16, 2), 256, 0, stream>>>(F1, R1, N);
    // hop 2: gather bf16 h1, write bf16 h2
    AggDir F2{h1fb, s2f, d2f, rsF, colF, h2fb, nullptr, nullptr, nullptr, nullptr};
    AggDir R2{h1rb, s2r, d2r, rsR, colR, h2rb, nullptr, nullptr, nullptr, nullptr};
    agg_kernel<<<dim3((N + 15) / 16, 2), 256, 0, stream>>>(F2, R2, N);

    wefft_kernel<<<(64 * 640 + 255) / 256, 256, 0, stream>>>(W, WeffT);
    gemm_mfma<<<(N + 127) / 128, 256, 0, stream>>>(xbf, h1fb, h2fb, h1rb, h2rb,
                                                   WeffT, bias, out, N);
}

// Round 25
// 256.719 us; speedup vs baseline: 1.1955x; 1.1080x over previous
//
#include <hip/hip_runtime.h>
#include <math.h>

#define F 128
#define OUTDIM 64
#define NEG 0.2f

typedef __attribute__((ext_vector_type(8))) short bf16x8;
typedef __attribute__((ext_vector_type(4))) float f32x4;

// ---------------- bf16 helpers ----------------
__device__ __forceinline__ float blo(unsigned u) { return __uint_as_float(u << 16); }
__device__ __forceinline__ float bhi(unsigned u) { return __uint_as_float(u & 0xFFFF0000u); }
__device__ __forceinline__ unsigned bpack(float a, float b) {  // rtne both
    unsigned ua = __float_as_uint(a), ub = __float_as_uint(b);
    ua += 0x7FFFu + ((ua >> 16) & 1u);
    ub += 0x7FFFu + ((ub >> 16) & 1u);
    return (ua >> 16) | (ub & 0xFFFF0000u);
}

// direct global->LDS DMA (16B/lane); dest = wave-uniform base + lane*16
__device__ __forceinline__ void gld_lds16(const void* g, void* l) {
    __builtin_amdgcn_global_load_lds(
        (const __attribute__((address_space(1))) unsigned*)g,
        (__attribute__((address_space(3))) unsigned*)l, 16, 0, 0);
}

// ---------------- utility ----------------
__global__ void zero_ints(int* __restrict__ p, int n) {
    int i = blockIdx.x * blockDim.x + threadIdx.x;
    if (i < n) p[i] = 0;
}

// ---------------- CSR build ----------------
// hist records each edge's arrival rank (atomicAdd return) so scatter needs NO atomics.
__global__ void hist_kernel(const int* __restrict__ src, const int* __restrict__ dst,
                            int* __restrict__ degF, int* __restrict__ degR,
                            int* __restrict__ rankF, int* __restrict__ rankR, int E) {
    int e = blockIdx.x * blockDim.x + threadIdx.x;
    if (e < E) {
        rankF[e] = atomicAdd(&degF[dst[e]], 1);
        rankR[e] = atomicAdd(&degR[src[e]], 1);
    }
}

__global__ void scan_pass1(const int* __restrict__ degF, const int* __restrict__ degR,
                           int* __restrict__ rsF, int* __restrict__ rsR,
                           int* __restrict__ bsums, int N) {
    const int arr = blockIdx.y;
    const int* deg = arr ? degR : degF;
    int* rs = arr ? rsR : rsF;
    int tid = threadIdx.x;
    int base = blockIdx.x * 1024 + tid * 4;
    int v[4];
#pragma unroll
    for (int i = 0; i < 4; i++) v[i] = (base + i < N) ? deg[base + i] : 0;
    int s1 = v[0] + v[1] + v[2] + v[3];
    __shared__ int sd[256];
    sd[tid] = s1;
    __syncthreads();
    for (int off = 1; off < 256; off <<= 1) {
        int t = (tid >= off) ? sd[tid - off] : 0;
        __syncthreads();
        sd[tid] += t;
        __syncthreads();
    }
    int run = sd[tid] - s1;
#pragma unroll
    for (int i = 0; i < 4; i++) {
        run += v[i];
        if (base + i < N) rs[base + i + 1] = run;
    }
    if (tid == 255) bsums[arr * 128 + blockIdx.x] = sd[255];
    if (tid == 0 && blockIdx.x == 0) rs[0] = 0;
}

__global__ void scan_pass2(int* __restrict__ bsums, int nb) {
    int arr = blockIdx.y;
    int tid = threadIdx.x;  // 128
    __shared__ int sd[128];
    int v = (tid < nb) ? bsums[arr * 128 + tid] : 0;
    sd[tid] = v;
    __syncthreads();
    for (int off = 1; off < 128; off <<= 1) {
        int t = (tid >= off) ? sd[tid - off] : 0;
        __syncthreads();
        sd[tid] += t;
        __syncthreads();
    }
    bsums[arr * 128 + tid] = sd[tid];
}

__global__ void scan_pass3(int* __restrict__ rsF, int* __restrict__ rsR,
                           const int* __restrict__ bsums, int N) {
    int arr = blockIdx.y;
    if (blockIdx.x == 0) return;
    int* rs = arr ? rsR : rsF;
    int off = bsums[arr * 128 + blockIdx.x - 1];
    int base = blockIdx.x * 1024 + threadIdx.x * 4;
#pragma unroll
    for (int i = 0; i < 4; i++)
        if (base + i < N) rs[base + i + 1] += off;
}

// atomic-free: position = rs[node] + precomputed rank
__global__ void scatter_kernel(const int* __restrict__ src, const int* __restrict__ dst,
                               const int* __restrict__ rsF, const int* __restrict__ rsR,
                               const int* __restrict__ rankF, const int* __restrict__ rankR,
                               int* __restrict__ colF, int* __restrict__ colR, int E) {
    int e = blockIdx.x * blockDim.x + threadIdx.x;
    if (e < E) {
        int s = src[e], d = dst[e];
        colF[rsF[d] + rankF[e]] = s;
        colR[rsR[s] + rankR[e]] = d;
    }
}

// ---------------- per-node attention scalars + bf16 feature copy ----------------
__global__ void sd4_kernel(const float* __restrict__ x,
                           const float* __restrict__ af_s, const float* __restrict__ af_d,
                           const float* __restrict__ ar_s, const float* __restrict__ ar_d,
                           float* __restrict__ sf, float* __restrict__ df,
                           float* __restrict__ sr, float* __restrict__ dr,
                           unsigned* __restrict__ xbf, int N) {
    int node = blockIdx.x * 4 + (threadIdx.x >> 6);
    int lane = threadIdx.x & 63;
    if (node >= N) return;
    const float2 xv = *(const float2*)&x[(size_t)node * F + 2 * lane];
    xbf[(size_t)node * 64 + lane] = bpack(xv.x, xv.y);
    float2 a;
    a = *(const float2*)&af_s[2 * lane]; float vsf = xv.x * a.x + xv.y * a.y;
    a = *(const float2*)&af_d[2 * lane]; float vdf = xv.x * a.x + xv.y * a.y;
    a = *(const float2*)&ar_s[2 * lane]; float vsr = xv.x * a.x + xv.y * a.y;
    a = *(const float2*)&ar_d[2 * lane]; float vdr = xv.x * a.x + xv.y * a.y;
#pragma unroll
    for (int off = 32; off > 0; off >>= 1) {
        vsf += __shfl_xor(vsf, off);
        vdf += __shfl_xor(vdf, off);
        vsr += __shfl_xor(vsr, off);
        vdr += __shfl_xor(vdr, off);
    }
    if (lane == 0) { sf[node] = vsf; df[node] = vdf; sr[node] = vsr; dr[node] = vdr; }
}

// ---------------- fused dual-direction attention hop ----------------
// quarter-wave (16 lanes) per node; blockIdx.y selects direction.
// bf16 rows (256 B), 8-deep gather pipeline (raw uint4 staging).
struct AggDir {
    const unsigned* hin_bf;  // [N][64]  bf16x2
    const float* s;          // [N]
    const float* d;          // [N]
    const int* rs;           // [N+1]
    const int* col;          // [E]
    unsigned* hout_bf;       // [N][64]  bf16x2
    const float* a_s;        // nullable: fused next-hop dots
    const float* a_d;
    float* s_out;
    float* d_out;
};

__global__ __launch_bounds__(256) void agg_kernel(AggDir D0, AggDir D1, int N) {
    AggDir P = blockIdx.y ? D1 : D0;
    int node = blockIdx.x * 16 + (threadIdx.x >> 4);
    int lane = threadIdx.x & 15;           // within quarter-wave
    int qbase = threadIdx.x & 48;          // quarter offset inside the wave
    if (node >= N) return;
    float di = P.d[node];
    int beg = P.rs[node], end = P.rs[node + 1];
    int deg = end - beg;
    float m = -INFINITY, l = 0.f;
    float4 a0 = make_float4(0.f, 0.f, 0.f, 0.f);
    float4 a1 = make_float4(0.f, 0.f, 0.f, 0.f);

    for (int base = 0; base < deg; base += 16) {
        int cnt = min(16, deg - base);
        int sj_l = 0;
        float e_l = -INFINITY;
        if (lane < cnt) {
            sj_l = P.col[beg + base + lane];
            float e = P.s[sj_l] + di;
            e_l = (e >= 0.f) ? e : NEG * e;
        }
        float bm = e_l;
#pragma unroll
        for (int off = 8; off > 0; off >>= 1) bm = fmaxf(bm, __shfl_xor(bm, off));
        float nm = fmaxf(m, bm);
        float p_l = (lane < cnt) ? __expf(e_l - nm) : 0.f;
        float ps = p_l;
#pragma unroll
        for (int off = 8; off > 0; off >>= 1) ps += __shfl_xor(ps, off);
        float sc = (m == -INFINITY) ? 0.f : __expf(m - nm);
        l = l * sc + ps;
        a0.x *= sc; a0.y *= sc; a0.z *= sc; a0.w *= sc;
        a1.x *= sc; a1.y *= sc; a1.z *= sc; a1.w *= sc;
        // 8-deep gather: stage raw bf16x2 lines (uint4), convert at FMA time
        for (int j0 = 0; j0 < cnt; j0 += 8) {
            int sj[8]; float p[8]; uint4 hb[8];
#pragma unroll
            for (int u = 0; u < 8; u++) {
                sj[u] = __shfl(sj_l, qbase + j0 + u);
                p[u]  = __shfl(p_l,  qbase + j0 + u);
            }
#pragma unroll
            for (int u = 0; u < 8; u++) {
                if (j0 + u < cnt) {  // uniform per quarter-wave
                    hb[u] = *(const uint4*)&P.hin_bf[(size_t)sj[u] * 64 + 4 * lane];
                } else {
                    hb[u] = make_uint4(0u, 0u, 0u, 0u);
                }
            }
#pragma unroll
            for (int u = 0; u < 8; u++) {
                a0.x += p[u] * blo(hb[u].x); a0.y += p[u] * bhi(hb[u].x);
                a0.z += p[u] * blo(hb[u].y); a0.w += p[u] * bhi(hb[u].y);
                a1.x += p[u] * blo(hb[u].z); a1.y += p[u] * bhi(hb[u].z);
                a1.z += p[u] * blo(hb[u].w); a1.w += p[u] * bhi(hb[u].w);
            }
        }
        m = nm;
    }

    float4 o0, o1;
    if (deg > 0) {
        float inv = 1.f / (l + 1e-16f);
        o0.x = a0.x * inv; o0.y = a0.y * inv; o0.z = a0.z * inv; o0.w = a0.w * inv;
        o1.x = a1.x * inv; o1.y = a1.y * inv; o1.z = a1.z * inv; o1.w = a1.w * inv;
    } else {
        o0 = make_float4(0.f, 0.f, 0.f, 0.f);
        o1 = o0;
    }
    uint4 hb;
    hb.x = bpack(o0.x, o0.y); hb.y = bpack(o0.z, o0.w);
    hb.z = bpack(o1.x, o1.y); hb.w = bpack(o1.z, o1.w);
    *(uint4*)&P.hout_bf[(size_t)node * 64 + 4 * lane] = hb;
    if (P.a_s) {
        float4 b0, b1;
        b0 = *(const float4*)&P.a_s[8 * lane];
        b1 = *(const float4*)&P.a_s[8 * lane + 4];
        float vs = o0.x * b0.x + o0.y * b0.y + o0.z * b0.z + o0.w * b0.w
                 + o1.x * b1.x + o1.y * b1.y + o1.z * b1.z + o1.w * b1.w;
        b0 = *(const float4*)&P.a_d[8 * lane];
        b1 = *(const float4*)&P.a_d[8 * lane + 4];
        float vd = o0.x * b0.x + o0.y * b0.y + o0.z * b0.z + o0.w * b0.w
                 + o1.x * b1.x + o1.y * b1.y + o1.z * b1.z + o1.w * b1.w;
#pragma unroll
        for (int off = 8; off > 0; off >>= 1) {
            vs += __shfl_xor(vs, off);
            vd += __shfl_xor(vd, off);
        }
        if (lane == 0) { P.s_out[node] = vs; P.d_out[node] = vd; }
    }
}

// ---------------- fold W blocks -> transposed bf16: WeffT[64][640] ----------------
__global__ void wefft_kernel(const float* __restrict__ W, unsigned short* __restrict__ Wt) {
    int i = blockIdx.x * blockDim.x + threadIdx.x;
    if (i >= 64 * 640) return;
    int n = i / 640, k = i % 640;
    float v;
    if (k < 128)      v = W[k * 64 + n] + W[(k + 384) * 64 + n];
    else if (k < 384) v = W[k * 64 + n];
    else              v = W[(k + 128) * 64 + n];
    Wt[(size_t)n * 640 + k] = (unsigned short)(bpack(v, 0.f) & 0xFFFFu);
}

// ---------------- final dense via MFMA + LDS staging (m97 pattern) ----------------
// R19-R24: every register-staged schedule pinned at 62us (compiler sinks loads
// to uses, VGPR 76 vs 192 requested -> depth ~2). global_load_lds bypasses
// registers entirely: per panel stage A-tile (32KB, 8 DMA/wave) + B-tile
// (16KB, 4 DMA/wave) -> barrier (vmcnt drain) -> swizzled ds_read + 32 MFMA.
// Swizzle col^=((row&7)<<4) applied on the GLOBAL source addr (linear LDS
// dest, rule #21); fragment reads then 2-way bank = free. 48KB -> 3 blk/CU.
__global__ __launch_bounds__(256) void gemm_mfma(
    const unsigned* __restrict__ XBF, const unsigned* __restrict__ H1FB,
    const unsigned* __restrict__ H2FB, const unsigned* __restrict__ H1RB,
    const unsigned* __restrict__ H2RB,
    const unsigned short* __restrict__ Wt,  // [64][640] bf16
    const float* __restrict__ bias, float* __restrict__ out, int N) {
    __shared__ unsigned Asm[8192];   // 32KB: 128 rows x 256B
    __shared__ unsigned Bsm[4096];   // 16KB: 64 rows x 256B
    int tid = threadIdx.x;
    int wid = tid >> 6;
    int lane = tid & 63;
    int r = lane & 15;
    int kg = lane >> 4;                   // k-group: byte col kg*16 within 64B step
    int rowBase = blockIdx.x * 128;
    int rl0 = wid * 32 + r;               // block-local rows of this thread's tiles
    int rl1 = rl0 + 16;
    const int xw = (r & 7) << 4;          // row-XOR for both rl0/rl1 (same &7)
    f32x4 acc[2][4];
#pragma unroll
    for (int m = 0; m < 2; m++)
#pragma unroll
        for (int c = 0; c < 4; c++) acc[m][c] = (f32x4){0.f, 0.f, 0.f, 0.f};

#define PANEL(SRC, KOFF)                                                         \
    {                                                                            \
        const char* asrc = (const char*)(SRC);                                   \
        const char* bsrc = (const char*)Wt + (size_t)(KOFF) * 2;                 \
        _Pragma("unroll")                                                        \
        for (int i = 0; i < 8; ++i) {                                            \
            int o = wid * 8192 + i * 1024 + (lane << 4);                         \
            int rowl = o >> 8, colb = o & 255;                                   \
            int scol = colb ^ ((rowl & 7) << 4);                                 \
            gld_lds16(asrc + (size_t)(rowBase + rowl) * 256 + scol,              \
                      &Asm[(wid * 8192 + i * 1024) >> 2]);                       \
        }                                                                        \
        _Pragma("unroll")                                                        \
        for (int i = 0; i < 4; ++i) {                                            \
            int o = wid * 4096 + i * 1024 + (lane << 4);                         \
            int rowl = o >> 8, colb = o & 255;                                   \
            int scol = colb ^ ((rowl & 7) << 4);                                 \
            gld_lds16(bsrc + (size_t)rowl * 1280 + scol,                         \
                      &Bsm[(wid * 4096 + i * 1024) >> 2]);                       \
        }                                                                        \
        __syncthreads();                                                         \
        _Pragma("unroll")                                                        \
        for (int tt = 0; tt < 4; ++tt) {                                         \
            int colb = tt * 64 + kg * 16;                                        \
            bf16x8 a0 = *(const bf16x8*)((const char*)Asm + rl0 * 256 + (colb ^ xw)); \
            bf16x8 a1 = *(const bf16x8*)((const char*)Asm + rl1 * 256 + (colb ^ xw)); \
            _Pragma("unroll")                                                    \
            for (int c = 0; c < 4; c++) {                                        \
                bf16x8 b = *(const bf16x8*)((const char*)Bsm + (c * 16 + r) * 256 + (colb ^ xw)); \
                acc[0][c] = __builtin_amdgcn_mfma_f32_16x16x32_bf16(a0, b, acc[0][c], 0, 0, 0); \
                acc[1][c] = __builtin_amdgcn_mfma_f32_16x16x32_bf16(a1, b, acc[1][c], 0, 0, 0); \
            }                                                                    \
        }                                                                        \
        __syncthreads();                                                         \
    }

    PANEL(XBF, 0)
    PANEL(H1FB, 128)
    PANEL(H2FB, 256)
    PANEL(H1RB, 384)
    PANEL(H2RB, 512)
#undef PANEL

#pragma unroll
    for (int m = 0; m < 2; m++)
#pragma unroll
        for (int c = 0; c < 4; c++) {
            int col = c * 16 + r;
            float bv = bias[col];
#pragma unroll
            for (int q = 0; q < 4; q++) {
                int row = rowBase + wid * 32 + m * 16 + kg * 4 + q;
                if (row < N) out[(size_t)row * 64 + col] = acc[m][c][q] + bv;
            }
        }
}

extern "C" void kernel_launch(void* const* d_in, const int* in_sizes, int n_in,
                              void* d_out, int out_size, void* d_ws, size_t ws_size,
                              hipStream_t stream) {
    const float* feature = (const float*)d_in[0];
    const int*   eidx    = (const int*)d_in[1];
    const float* af_s    = (const float*)d_in[2];
    const float* af_d    = (const float*)d_in[3];
    const float* ar_s    = (const float*)d_in[4];
    const float* ar_d    = (const float*)d_in[5];
    const float* W       = (const float*)d_in[6];
    const float* bias    = (const float*)d_in[7];
    float* out = (float*)d_out;
    const int N = in_sizes[0] / F;
    const int E = in_sizes[1] / 2;
    const int* src = eidx;
    const int* dst = eidx + E;

    char* ws = (char*)d_ws;
    size_t off = 0;
    auto alloc = [&](size_t b) { size_t r = off; off = (off + b + 255) & ~(size_t)255; return r; };
    unsigned* xbf  = (unsigned*)(ws + alloc((size_t)N * 64 * 4));
    unsigned* h1fb = (unsigned*)(ws + alloc((size_t)N * 64 * 4));
    unsigned* h1rb = (unsigned*)(ws + alloc((size_t)N * 64 * 4));
    unsigned* h2fb = (unsigned*)(ws + alloc((size_t)N * 64 * 4));
    unsigned* h2rb = (unsigned*)(ws + alloc((size_t)N * 64 * 4));
    int*   rsF   = (int*)(ws + alloc((size_t)(N + 1) * 4));
    int*   rsR   = (int*)(ws + alloc((size_t)(N + 1) * 4));
    int*   colF  = (int*)(ws + alloc((size_t)E * 4));
    int*   colR  = (int*)(ws + alloc((size_t)E * 4));
    int*   rankF = (int*)(ws + alloc((size_t)E * 4));
    int*   rankR = (int*)(ws + alloc((size_t)E * 4));
    int*   ints2 = (int*)(ws + alloc((size_t)2 * N * 4));
    int *degF = ints2, *degR = ints2 + N;
    float* fls8 = (float*)(ws + alloc((size_t)8 * N * 4));
    float *sf = fls8, *df = fls8 + N, *sr = fls8 + 2 * (size_t)N, *dr = fls8 + 3 * (size_t)N;
    float *s2f = fls8 + 4 * (size_t)N, *d2f = fls8 + 5 * (size_t)N;
    float *s2r = fls8 + 6 * (size_t)N, *d2r = fls8 + 7 * (size_t)N;
    int*   bsums = (int*)(ws + alloc(256 * 4));
    unsigned short* WeffT = (unsigned short*)(ws + alloc(64 * 640 * 2));

    const int nb = (N + 1023) / 1024;
    zero_ints<<<(2 * N + 255) / 256, 256, 0, stream>>>(ints2, 2 * N);
    hist_kernel<<<(E + 255) / 256, 256, 0, stream>>>(src, dst, degF, degR, rankF, rankR, E);
    scan_pass1<<<dim3(nb, 2), 256, 0, stream>>>(degF, degR, rsF, rsR, bsums, N);
    scan_pass2<<<dim3(1, 2), 128, 0, stream>>>(bsums, nb);
    scan_pass3<<<dim3(nb, 2), 256, 0, stream>>>(rsF, rsR, bsums, N);
    scatter_kernel<<<(E + 255) / 256, 256, 0, stream>>>(src, dst, rsF, rsR, rankF, rankR,
                                                        colF, colR, E);
    sd4_kernel<<<(N + 3) / 4, 256, 0, stream>>>(feature, af_s, af_d, ar_s, ar_d,
                                                sf, df, sr, dr, xbf, N);

    // hop 1: gather bf16 feature (xbf), write bf16 h1 + fused next-hop dots
    AggDir F1{xbf, sf, df, rsF, colF, h1fb, af_s, af_d, s2f, d2f};
    AggDir R1{xbf, sr, dr, rsR, colR, h1rb, ar_s, ar_d, s2r, d2r};
    agg_kernel<<<dim3((N + 15) / 16, 2), 256, 0, stream>>>(F1, R1, N);
    // hop 2: gather bf16 h1, write bf16 h2
    AggDir F2{h1fb, s2f, d2f, rsF, colF, h2fb, nullptr, nullptr, nullptr, nullptr};
    AggDir R2{h1rb, s2r, d2r, rsR, colR, h2rb, nullptr, nullptr, nullptr, nullptr};
    agg_kernel<<<dim3((N + 15) / 16, 2), 256, 0, stream>>>(F2, R2, N);

    wefft_kernel<<<(64 * 640 + 255) / 256, 256, 0, stream>>>(W, WeffT);
    gemm_mfma<<<(N + 127) / 128, 256, 0, stream>>>(xbf, h1fb, h2fb, h1rb, h2rb,
                                                   WeffT, bias, out, N);
}